// Round 20
// baseline (131.857 us; speedup 1.0000x reference)
//
#include <hip/hip_runtime.h>

#define DEVI static __device__ __forceinline__

typedef unsigned short u16;
typedef unsigned int u32;
typedef __attribute__((ext_vector_type(8))) __bf16 bf16x8;
typedef __attribute__((ext_vector_type(8))) short short8;
typedef __attribute__((ext_vector_type(4))) float f32x4;
typedef __attribute__((ext_vector_type(16))) float f32x16;
typedef __attribute__((ext_vector_type(4))) u32 u32x4;

DEVI u16 f2bf(float f) {
  union { float f; u32 u; } v; v.f = f;
  u32 r = v.u + 0x7fffu + ((v.u >> 16) & 1u);  // RNE
  return (u16)(r >> 16);
}

DEVI u16 bfc(float f) {
  union { __bf16 b; u16 u; } v; v.b = (__bf16)f; return v.u;
}

// two f32 -> one u32 of packed bf16; in-lane, compiler fuses to v_cvt_pk_bf16_f32
DEVI u32 pk2bf(float lo, float hi) {
  union { struct { __bf16 l, h; } s; u32 u; } c;
  c.s.l = (__bf16)lo; c.s.h = (__bf16)hi;
  return c.u;
}

DEVI void gload16(const void* g, void* l) {
  __builtin_amdgcn_global_load_lds(
      (const __attribute__((address_space(1))) void*)g,
      (__attribute__((address_space(3))) void*)l,
      16, 0, 0);
}

// ---- prep: weights transpose-convert (z<4), mask bias (z==4), x->bf16 (z=5..7) ----
__global__ void k_prep(const float* __restrict__ W0, const float* __restrict__ W1,
                       const float* __restrict__ W2, const float* __restrict__ W3,
                       u16* __restrict__ Wtb,
                       const int* __restrict__ msk, float* __restrict__ bias,
                       const float* __restrict__ xq, const float* __restrict__ xk,
                       const float* __restrict__ xv, u16* __restrict__ xbf) {
  const int z = blockIdx.z;
  const int tid = threadIdx.y * 32 + threadIdx.x;
  if (z == 4) {
    if (blockIdx.x < 16 && blockIdx.y == 0) {
      const int i = blockIdx.x * 256 + tid;
      bias[i] = (msk[i] == 1) ? 0.f : -1e30f;
    }
    return;
  }
  if (z >= 5) {
    const int xi = z - 5;
    const float* in = (xi == 0) ? xq : ((xi == 1) ? xk : xv);
    u16* out = xbf + (size_t)xi * 4194304;
    const int lin = (blockIdx.y * 32 + blockIdx.x) * 256 + tid;
#pragma unroll
    for (int j = 0; j < 4; ++j) {
      const int idx = j * 262144 + lin;
      const float4 v = reinterpret_cast<const float4*>(in)[idx];
      ushort4 s;
      s.x = f2bf(v.x); s.y = f2bf(v.y); s.z = f2bf(v.z); s.w = f2bf(v.w);
      reinterpret_cast<ushort4*>(out)[idx] = s;
    }
    return;
  }
  const float* W = (z == 0) ? W0 : ((z == 1) ? W1 : ((z == 2) ? W2 : W3));
  u16* Wt = Wtb + (size_t)z * 1024 * 1024;
  __shared__ float tl[32][33];
  const int n0 = blockIdx.x * 32, k0 = blockIdx.y * 32;
  const int tx = threadIdx.x, ty = threadIdx.y;
#pragma unroll
  for (int r = ty; r < 32; r += 8)
    tl[r][tx] = W[(size_t)(k0 + r) * 1024 + n0 + tx];
  __syncthreads();
#pragma unroll
  for (int r = ty; r < 32; r += 8)
    Wt[(size_t)(n0 + r) * 1024 + k0 + tx] = f2bf(tl[tx][r]);
}

// ---------------- GEMM: C[M][N] = (A[M][K](bf16) * Bt[N][K](bf16) + bias) * scale ----
// BM=128, BN in {128,64}. BK=128 executed as FOUR linear [rows][32] sub-tiles per
// barrier pair (R18's proven lever extended: barrier-pair count 16 -> 8; the
// vmcnt(0)+barrier drain is the m97 structure's stall and scales with barrier
// count). gload_lds destinations stay linear; fragment reads unchanged.
// z==2 with Vt != nullptr writes transposed Vt.
DEVI void store1(u16* C, size_t i, float v) { C[i] = f2bf(v); }
DEVI void store1(float* C, size_t i, float v) { C[i] = v; }

template <typename OutT, int BN>
__global__ __launch_bounds__(256, 2) void k_gemm_bt(
    const u16* __restrict__ Abase, long aZ,
    const u16* __restrict__ Btbase, long bZ,
    const float* __restrict__ bias0, const float* __restrict__ bias1,
    const float* __restrict__ bias2,
    float s0, float s1, float s2,
    OutT* __restrict__ Cbase, long cZ, u16* __restrict__ Vt,
    int M, int N, int K) {
  const int z = blockIdx.z;
  const u16* A  = Abase + (size_t)z * aZ;
  const u16* Bt = Btbase + (size_t)z * bZ;
  OutT* C = Cbase + (size_t)z * cZ;
  const float* bias = (z == 0) ? bias0 : ((z == 1) ? bias1 : bias2);
  const float scl = (z == 0) ? s0 : ((z == 1) ? s1 : s2);

  constexpr int NF = BN / 32;  // n-frags per wave
  __shared__ u16 lsA[4][128 * 32];
  __shared__ u16 lsB[4][BN * 32];

  const int t = threadIdx.x;
  const int w = t >> 6, ln = t & 63;
  const int l15 = ln & 15, lhi = ln >> 4;
  const int wr = w >> 1, wc = w & 1;
  const int m0 = blockIdx.x * 128, n0 = blockIdx.y * BN;

  f32x4 acc[4][NF] = {};

  const int cb2 = (t & 3) << 3;

  for (int kt = 0; kt < K; kt += 128) {
#pragma unroll
    for (int h4 = 0; h4 < 4; ++h4) {
#pragma unroll
      for (int i = 0; i < 2; ++i) {
        const int row = (i * 256 + t) >> 2;
        gload16(A + (size_t)(m0 + row) * K + kt + h4 * 32 + cb2,
                (char*)lsA[h4] + (i * 256 + w * 64) * 16);
      }
#pragma unroll
      for (int i = 0; i < BN / 64; ++i) {
        const int row = (i * 256 + t) >> 2;
        gload16(Bt + (size_t)(n0 + row) * K + kt + h4 * 32 + cb2,
                (char*)lsB[h4] + (i * 256 + w * 64) * 16);
      }
    }
    __syncthreads();

#pragma unroll
    for (int h4 = 0; h4 < 4; ++h4) {
      bf16x8 af[4], bf_[NF];
#pragma unroll
      for (int m = 0; m < 4; ++m)
        af[m] = *reinterpret_cast<const bf16x8*>(
            &lsA[h4][(wr * 64 + m * 16 + l15) * 32 + lhi * 8]);
#pragma unroll
      for (int n = 0; n < NF; ++n)
        bf_[n] = *reinterpret_cast<const bf16x8*>(
            &lsB[h4][(wc * (BN / 2) + n * 16 + l15) * 32 + lhi * 8]);
#pragma unroll
      for (int m = 0; m < 4; ++m)
#pragma unroll
        for (int n = 0; n < NF; ++n)
          acc[m][n] = __builtin_amdgcn_mfma_f32_16x16x32_bf16(af[m], bf_[n], acc[m][n], 0, 0, 0);
    }
    __syncthreads();
  }

  if (Vt != nullptr && z == 2) {
    // transposed write: Vt[(b*1024 + c)][s], 4 consecutive tokens per quad
#pragma unroll
    for (int n = 0; n < NF; ++n) {
      const int c = n0 + wc * (BN / 2) + n * 16 + l15;
      const float bv = bias[c];
#pragma unroll
      for (int m = 0; m < 4; ++m) {
        const int r = m0 + wr * 64 + m * 16 + lhi * 4;
        ushort4 s4;
#pragma unroll
        for (int j = 0; j < 4; ++j) ((u16*)&s4)[j] = f2bf(acc[m][n][j] + bv);
        *reinterpret_cast<ushort4*>(
            &Vt[((size_t)((r >> 11) * 1024 + c)) * 2048 + (r & 2047)]) = s4;
      }
    }
    return;
  }

#pragma unroll
  for (int n = 0; n < NF; ++n) {
    const int c = n0 + wc * (BN / 2) + n * 16 + l15;
    const float bv = bias[c];
#pragma unroll
    for (int m = 0; m < 4; ++m)
#pragma unroll
      for (int j = 0; j < 4; ++j) {
        const int r = m0 + wr * 64 + m * 16 + lhi * 4 + j;
        store1(C, (size_t)r * N + c, (acc[m][n][j] + bv) * scl);
      }
  }
}

// ---------------- flash attention (32x32 MFMA, in-lane P, QK(t+1)||SM(t)) ------
// grid 512 flat, XCD-grouped. 4 waves/block, 32 q-rows/wave (q=lane&31). KVBLK=64.
// Pipeline: QK^T(t+1) (MFMA) issues BEFORE SM(t) (VALU). K LDS 3-deep (write
// lookahead +3), V 2-deep (+2), ONE barrier/tile. Mask bias pre-loads INITIALIZE
// the QK accumulator. P in-lane via sigma-staged lsV. T13 defer-max.
// Tree-reduced max/sum; pk2bf packed P. No s_setprio (R17 ablation: null).
__global__ __launch_bounds__(256, 2) void k_attn(
    const u16* __restrict__ Q, const u16* __restrict__ K, const u16* __restrict__ Vt,
    const float* __restrict__ MB, u16* __restrict__ O) {
  __shared__ u16 lsK[3][64][72];
  __shared__ u16 lsV[2][64][72];

  const int t = threadIdx.x, w = t >> 6, ln = t & 63;
  const int l31 = ln & 31, h = ln >> 5, h8 = h * 8;
  const int fid = blockIdx.x;                // 0..511
  const int xcd = fid & 7, slot = fid >> 3;  // 0..63
  const int pair = xcd * 4 + (slot >> 4);    // 0..31
  const int qt = slot & 15;
  const int hh = pair & 15, b = pair >> 4;

  const size_t rowQ = (size_t)b * 2048 + qt * 128 + w * 32;
  const int hc = hh * 64;

  const int srow = t >> 3, scol = (t & 7) << 3;
  const u16* Kg = K + ((size_t)b * 2048 + srow) * 1024 + hc + scol;
  const int half = t & 1;
  const int g16 = ((t & 7) >> 1) << 4;
  const u16* VgA = Vt + ((size_t)(b * 1024 + hc) + srow) * 2048 + g16 + 4 * half;
  const float* MBb = MB + b * 2048;

  bf16x8 qb[4];
#pragma unroll
  for (int ks = 0; ks < 4; ++ks)
    qb[ks] = *reinterpret_cast<const bf16x8*>(
        &Q[(rowQ + l31) * 1024 + hc + ks * 16 + h8]);

  f32x16 o[2];
#pragma unroll
  for (int i = 0; i < 16; ++i) { o[0][i] = 0.f; o[1][i] = 0.f; }
  float mrow = -1e30f, lsum = 0.f;

  // prologue: stage K(0..2) and V(0..1)
#pragma unroll
  for (int p = 0; p < 3; ++p) {
    const short8 a = *reinterpret_cast<const short8*>(Kg + (size_t)(p * 64) * 1024);
    const short8 c = *reinterpret_cast<const short8*>(Kg + (size_t)(p * 64 + 32) * 1024);
    *reinterpret_cast<short8*>(&lsK[p][srow][scol]) = a;
    *reinterpret_cast<short8*>(&lsK[p][32 + srow][scol]) = c;
  }
#pragma unroll
  for (int p = 0; p < 2; ++p) {
    const ushort4 a = *reinterpret_cast<const ushort4*>(VgA + p * 64);
    const ushort4 b4 = *reinterpret_cast<const ushort4*>(VgA + p * 64 + 8);
    const ushort4 c = *reinterpret_cast<const ushort4*>(VgA + 32 * 2048 + p * 64);
    const ushort4 d = *reinterpret_cast<const ushort4*>(VgA + 32 * 2048 + p * 64 + 8);
    *reinterpret_cast<ushort4*>(&lsV[p][srow][scol]) = a;
    *reinterpret_cast<ushort4*>(&lsV[p][srow][scol + 4]) = b4;
    *reinterpret_cast<ushort4*>(&lsV[p][32 + srow][scol]) = c;
    *reinterpret_cast<ushort4*>(&lsV[p][32 + srow][scol + 4]) = d;
  }
  __syncthreads();

  // QK(0) -> stA (bias-initialized accumulator)
  f32x16 stA[2], stB[2];
#pragma unroll
  for (int f = 0; f < 2; ++f)
#pragma unroll
    for (int rg = 0; rg < 4; ++rg) {
      const f32x4 bv = *reinterpret_cast<const f32x4*>(&MBb[f * 32 + rg * 8 + h * 4]);
#pragma unroll
      for (int jj = 0; jj < 4; ++jj) stA[f][rg * 4 + jj] = bv[jj];
    }
#pragma unroll
  for (int ks = 0; ks < 4; ++ks) {
    const bf16x8 kb0 = *reinterpret_cast<const bf16x8*>(&lsK[0][l31][ks * 16 + h8]);
    const bf16x8 kb1 = *reinterpret_cast<const bf16x8*>(&lsK[0][32 + l31][ks * 16 + h8]);
    stA[0] = __builtin_amdgcn_mfma_f32_32x32x16_bf16(kb0, qb[ks], stA[0], 0, 0, 0);
    stA[1] = __builtin_amdgcn_mfma_f32_32x32x16_bf16(kb1, qb[ks], stA[1], 0, 0, 0);
  }

#define ATTN_BODY(T, CUR, NXT, SW)                                                  \
  {                                                                                 \
    const int tK = ((T) + 3) & 31, tV = ((T) + 2) & 31, tB = ((T) + 1) & 31;        \
    const short8 rk0 = *reinterpret_cast<const short8*>(Kg + (size_t)(tK * 64) * 1024); \
    const short8 rk1 = *reinterpret_cast<const short8*>(Kg + (size_t)(tK * 64 + 32) * 1024); \
    const ushort4 rv0a = *reinterpret_cast<const ushort4*>(VgA + tV * 64);          \
    const ushort4 rv0b = *reinterpret_cast<const ushort4*>(VgA + tV * 64 + 8);      \
    const ushort4 rv1a = *reinterpret_cast<const ushort4*>(VgA + 32 * 2048 + tV * 64); \
    const ushort4 rv1b = *reinterpret_cast<const ushort4*>(VgA + 32 * 2048 + tV * 64 + 8); \
    const int sK = ((SW) == 2) ? 0 : (SW) + 1;                                      \
    _Pragma("unroll")                                                               \
    for (int f = 0; f < 2; ++f)                                                     \
      _Pragma("unroll")                                                             \
      for (int rg = 0; rg < 4; ++rg) {                                              \
        const f32x4 bv = *reinterpret_cast<const f32x4*>(                           \
            &MBb[tB * 64 + f * 32 + rg * 8 + h * 4]);                               \
        _Pragma("unroll")                                                           \
        for (int jj = 0; jj < 4; ++jj) NXT[f][rg * 4 + jj] = bv[jj];                \
      }                                                                             \
    _Pragma("unroll")                                                               \
    for (int ks = 0; ks < 4; ++ks) {                                                \
      const bf16x8 kb0 = *reinterpret_cast<const bf16x8*>(&lsK[sK][l31][ks * 16 + h8]); \
      const bf16x8 kb1 = *reinterpret_cast<const bf16x8*>(&lsK[sK][32 + l31][ks * 16 + h8]); \
      NXT[0] = __builtin_amdgcn_mfma_f32_32x32x16_bf16(kb0, qb[ks], NXT[0], 0, 0, 0); \
      NXT[1] = __builtin_amdgcn_mfma_f32_32x32x16_bf16(kb1, qb[ks], NXT[1], 0, 0, 0); \
    }                                                                               \
    float m0 = CUR[0][0], m1 = CUR[0][1], m2 = CUR[0][2], m3 = CUR[0][3];           \
    _Pragma("unroll")                                                               \
    for (int i = 4; i < 16; i += 4) {                                               \
      m0 = fmaxf(m0, CUR[0][i + 0]); m1 = fmaxf(m1, CUR[0][i + 1]);                 \
      m2 = fmaxf(m2, CUR[0][i + 2]); m3 = fmaxf(m3, CUR[0][i + 3]);                 \
    }                                                                               \
    _Pragma("unroll")                                                               \
    for (int i = 0; i < 16; i += 4) {                                               \
      m0 = fmaxf(m0, CUR[1][i + 0]); m1 = fmaxf(m1, CUR[1][i + 1]);                 \
      m2 = fmaxf(m2, CUR[1][i + 2]); m3 = fmaxf(m3, CUR[1][i + 3]);                 \
    }                                                                               \
    float tm = fmaxf(fmaxf(m0, m1), fmaxf(m2, m3));                                 \
    tm = fmaxf(tm, __shfl_xor(tm, 32, 64));                                         \
    const bool trig = tm > mrow + 8.f;                                              \
    if (__any(trig)) {                                                              \
      const float al = trig ? __builtin_amdgcn_exp2f(mrow - tm) : 1.f;              \
      if (trig) mrow = tm;                                                          \
      lsum *= al;                                                                   \
      _Pragma("unroll")                                                             \
      for (int f = 0; f < 2; ++f)                                                   \
        _Pragma("unroll")                                                           \
        for (int i = 0; i < 16; ++i) o[f][i] *= al;                                 \
    }                                                                               \
    float r0 = 0.f, r1 = 0.f, r2 = 0.f, r3 = 0.f;                                   \
    _Pragma("unroll")                                                               \
    for (int f = 0; f < 2; ++f)                                                     \
      _Pragma("unroll")                                                             \
      for (int i = 0; i < 16; i += 4) {                                             \
        const float p0 = __builtin_amdgcn_exp2f(CUR[f][i + 0] - mrow);              \
        const float p1 = __builtin_amdgcn_exp2f(CUR[f][i + 1] - mrow);              \
        const float p2 = __builtin_amdgcn_exp2f(CUR[f][i + 2] - mrow);              \
        const float p3 = __builtin_amdgcn_exp2f(CUR[f][i + 3] - mrow);              \
        CUR[f][i + 0] = p0; CUR[f][i + 1] = p1;                                     \
        CUR[f][i + 2] = p2; CUR[f][i + 3] = p3;                                     \
        r0 += p0; r1 += p1; r2 += p2; r3 += p3;                                     \
      }                                                                             \
    lsum += (r0 + r1) + (r2 + r3);                                                  \
    _Pragma("unroll")                                                               \
    for (int f = 0; f < 2; ++f) {                                                   \
      u32 pk[8];                                                                    \
      _Pragma("unroll")                                                             \
      for (int i = 0; i < 8; ++i)                                                   \
        pk[i] = pk2bf(CUR[f][2 * i], CUR[f][2 * i + 1]);                            \
      _Pragma("unroll")                                                             \
      for (int s = 0; s < 2; ++s) {                                                 \
        u32x4 pw;                                                                   \
        pw[0] = pk[4 * s + 0]; pw[1] = pk[4 * s + 1];                               \
        pw[2] = pk[4 * s + 2]; pw[3] = pk[4 * s + 3];                               \
        const bf16x8 pb = __builtin_bit_cast(bf16x8, pw);                           \
        const int ks = f * 2 + s;                                                   \
        _Pragma("unroll")                                                           \
        for (int df2 = 0; df2 < 2; ++df2) {                                         \
          const bf16x8 vt = *reinterpret_cast<const bf16x8*>(                       \
              &lsV[(T) & 1][df2 * 32 + l31][ks * 16 + h8]);                         \
          o[df2] = __builtin_amdgcn_mfma_f32_32x32x16_bf16(vt, pb, o[df2], 0, 0, 0); \
        }                                                                           \
      }                                                                             \
    }                                                                               \
    __syncthreads();                                                                \
    *reinterpret_cast<short8*>(&lsK[SW][srow][scol]) = rk0;                         \
    *reinterpret_cast<short8*>(&lsK[SW][32 + srow][scol]) = rk1;                    \
    *reinterpret_cast<ushort4*>(&lsV[(T) & 1][srow][scol]) = rv0a;                  \
    *reinterpret_cast<ushort4*>(&lsV[(T) & 1][srow][scol + 4]) = rv0b;              \
    *reinterpret_cast<ushort4*>(&lsV[(T) & 1][32 + srow][scol]) = rv1a;             \
    *reinterpret_cast<ushort4*>(&lsV[(T) & 1][32 + srow][scol + 4]) = rv1b;         \
  }

  int sw = 0;
  for (int t2 = 0; t2 < 32; t2 += 2) {
    ATTN_BODY(t2, stA, stB, sw);
    sw = (sw == 2) ? 0 : sw + 1;
    ATTN_BODY(t2 + 1, stB, stA, sw);
    sw = (sw == 2) ? 0 : sw + 1;
  }
#undef ATTN_BODY

  // epilogue: O[q][d], q = l31, d = df2*32 + 8*rg + 4h + jj
  const float ltot = lsum + __shfl_xor(lsum, 32, 64);
  const float inv = 1.f / ltot;
#pragma unroll
  for (int df2 = 0; df2 < 2; ++df2)
#pragma unroll
    for (int rg = 0; rg < 4; ++rg) {
      ushort4 s4;
      s4.x = bfc(o[df2][rg * 4 + 0] * inv);
      s4.y = bfc(o[df2][rg * 4 + 1] * inv);
      s4.z = bfc(o[df2][rg * 4 + 2] * inv);
      s4.w = bfc(o[df2][rg * 4 + 3] * inv);
      *reinterpret_cast<ushort4*>(
          &O[(rowQ + l31) * 1024 + hc + df2 * 32 + rg * 8 + h * 4]) = s4;
    }
}

extern "C" void kernel_launch(void* const* d_in, const int* in_sizes, int n_in,
                              void* d_out, int out_size, void* d_ws, size_t ws_size,
                              hipStream_t stream) {
  const float* x_q = (const float*)d_in[0];
  const float* x_k = (const float*)d_in[1];
  const float* x_v = (const float*)d_in[2];
  const int*   msk = (const int*)d_in[3];
  const float* Wq  = (const float*)d_in[4];
  const float* bq  = (const float*)d_in[5];
  const float* Wk  = (const float*)d_in[6];
  const float* bk  = (const float*)d_in[7];
  const float* Wv  = (const float*)d_in[8];
  const float* bv  = (const float*)d_in[9];
  const float* Wo  = (const float*)d_in[10];
  const float* bo  = (const float*)d_in[11];

  const size_t NTOK = 4096, H = 1024;
  u16* xbf  = (u16*)d_ws;            // 3 * 4096*1024 bf16
  u16* wt   = xbf + 3 * NTOK * H;    // 4 * 1024*1024 bf16 (transposed weights)
  u16* qkv  = wt  + 4 * H * H;       // Q,K row-major; V slot holds Vt (transposed)
  u16* aout = qkv + 3 * NTOK * H;    // 4096*1024 bf16
  float* mb = (float*)(aout + NTOK * H);  // 4096 floats
  u16* vtb  = qkv + 2 * NTOK * H;    // Vt[b*1024 + c][s] (reuses V slot)

  // prep: weights (z 0-3), mask bias (z 4), x fp32->bf16 (z 5-7)
  k_prep<<<dim3(32, 32, 8), dim3(32, 8), 0, stream>>>(
      Wq, Wk, Wv, Wo, wt, msk, mb, x_q, x_k, x_v, xbf);

  // Q,K,V = x{q,k,v} @ W{q,k,v} + b{q,k,v}; all-async staging, BK=128 quad-subtile.
  // Q scaled by 0.125*log2(e) for exp2 softmax; z==2 writes transposed Vt.
  const float qscale = 0.125f * 1.4426950408889634f;
  k_gemm_bt<u16, 128><<<dim3(32, 8, 3), dim3(256), 0, stream>>>(
      xbf, (long)(NTOK * H), wt, (long)(H * H), bq, bk, bv,
      qscale, 1.f, 1.f,
      qkv, (long)(NTOK * H), vtb, 4096, 1024, 1024);

  // attention (flat grid, XCD-grouped mapping inside)
  k_attn<<<dim3(512), dim3(256), 0, stream>>>(
      qkv, qkv + NTOK * H, vtb, mb, aout);

  // out = attn_out @ Wo + bo (fp32 output); BN=64 -> 512 blocks = 2/CU
  k_gemm_bt<float, 64><<<dim3(32, 16, 1), dim3(256), 0, stream>>>(
      aout, 0L, wt + 3 * H * H, 0L, bo, bo, bo,
      1.f, 1.f, 1.f,
      (float*)d_out, 0L, nullptr, 4096, 1024, 1024);
}

// Round 21
// 129.751 us; speedup vs baseline: 1.0162x; 1.0162x over previous
//
#include <hip/hip_runtime.h>

#define DEVI static __device__ __forceinline__

typedef unsigned short u16;
typedef unsigned int u32;
typedef __attribute__((ext_vector_type(8))) __bf16 bf16x8;
typedef __attribute__((ext_vector_type(8))) short short8;
typedef __attribute__((ext_vector_type(4))) float f32x4;
typedef __attribute__((ext_vector_type(16))) float f32x16;
typedef __attribute__((ext_vector_type(4))) u32 u32x4;

DEVI u16 f2bf(float f) {
  union { float f; u32 u; } v; v.f = f;
  u32 r = v.u + 0x7fffu + ((v.u >> 16) & 1u);  // RNE
  return (u16)(r >> 16);
}

DEVI u16 bfc(float f) {
  union { __bf16 b; u16 u; } v; v.b = (__bf16)f; return v.u;
}

// two f32 -> one u32 of packed bf16; in-lane, compiler fuses to v_cvt_pk_bf16_f32
DEVI u32 pk2bf(float lo, float hi) {
  union { struct { __bf16 l, h; } s; u32 u; } c;
  c.s.l = (__bf16)lo; c.s.h = (__bf16)hi;
  return c.u;
}

DEVI void gload16(const void* g, void* l) {
  __builtin_amdgcn_global_load_lds(
      (const __attribute__((address_space(1))) void*)g,
      (__attribute__((address_space(3))) void*)l,
      16, 0, 0);
}

// ---- prep: weights transpose-convert (z<4), mask bias (z==4), x->bf16 (z=5..7) ----
__global__ void k_prep(const float* __restrict__ W0, const float* __restrict__ W1,
                       const float* __restrict__ W2, const float* __restrict__ W3,
                       u16* __restrict__ Wtb,
                       const int* __restrict__ msk, float* __restrict__ bias,
                       const float* __restrict__ xq, const float* __restrict__ xk,
                       const float* __restrict__ xv, u16* __restrict__ xbf) {
  const int z = blockIdx.z;
  const int tid = threadIdx.y * 32 + threadIdx.x;
  if (z == 4) {
    if (blockIdx.x < 16 && blockIdx.y == 0) {
      const int i = blockIdx.x * 256 + tid;
      bias[i] = (msk[i] == 1) ? 0.f : -1e30f;
    }
    return;
  }
  if (z >= 5) {
    const int xi = z - 5;
    const float* in = (xi == 0) ? xq : ((xi == 1) ? xk : xv);
    u16* out = xbf + (size_t)xi * 4194304;
    const int lin = (blockIdx.y * 32 + blockIdx.x) * 256 + tid;
#pragma unroll
    for (int j = 0; j < 4; ++j) {
      const int idx = j * 262144 + lin;
      const float4 v = reinterpret_cast<const float4*>(in)[idx];
      ushort4 s;
      s.x = f2bf(v.x); s.y = f2bf(v.y); s.z = f2bf(v.z); s.w = f2bf(v.w);
      reinterpret_cast<ushort4*>(out)[idx] = s;
    }
    return;
  }
  const float* W = (z == 0) ? W0 : ((z == 1) ? W1 : ((z == 2) ? W2 : W3));
  u16* Wt = Wtb + (size_t)z * 1024 * 1024;
  __shared__ float tl[32][33];
  const int n0 = blockIdx.x * 32, k0 = blockIdx.y * 32;
  const int tx = threadIdx.x, ty = threadIdx.y;
#pragma unroll
  for (int r = ty; r < 32; r += 8)
    tl[r][tx] = W[(size_t)(k0 + r) * 1024 + n0 + tx];
  __syncthreads();
#pragma unroll
  for (int r = ty; r < 32; r += 8)
    Wt[(size_t)(n0 + r) * 1024 + k0 + tx] = f2bf(tl[tx][r]);
}

// ---------------- GEMM: C[M][N] = (A[M][K](bf16) * Bt[N][K](bf16) + bias) * scale ----
// BM=128, BN in {128,64}. BK=64 executed as TWO linear [rows][32] sub-tiles per
// barrier pair (halves the vmcnt(0)+barrier drains -- the m97 structure's known
// ~20% stall -- while keeping gload_lds destinations linear and the verified
// 64B-row-stride fragment reads). z==2 with Vt != nullptr writes transposed Vt.
DEVI void store1(u16* C, size_t i, float v) { C[i] = f2bf(v); }
DEVI void store1(float* C, size_t i, float v) { C[i] = v; }

template <typename OutT, int BN>
__global__ __launch_bounds__(256, 2) void k_gemm_bt(
    const u16* __restrict__ Abase, long aZ,
    const u16* __restrict__ Btbase, long bZ,
    const float* __restrict__ bias0, const float* __restrict__ bias1,
    const float* __restrict__ bias2,
    float s0, float s1, float s2,
    OutT* __restrict__ Cbase, long cZ, u16* __restrict__ Vt,
    int M, int N, int K) {
  const int z = blockIdx.z;
  const u16* A  = Abase + (size_t)z * aZ;
  const u16* Bt = Btbase + (size_t)z * bZ;
  OutT* C = Cbase + (size_t)z * cZ;
  const float* bias = (z == 0) ? bias0 : ((z == 1) ? bias1 : bias2);
  const float scl = (z == 0) ? s0 : ((z == 1) ? s1 : s2);

  constexpr int NF = BN / 32;  // n-frags per wave
  __shared__ u16 lsA[2][128 * 32];
  __shared__ u16 lsB[2][BN * 32];

  const int t = threadIdx.x;
  const int w = t >> 6, ln = t & 63;
  const int l15 = ln & 15, lhi = ln >> 4;
  const int wr = w >> 1, wc = w & 1;
  const int m0 = blockIdx.x * 128, n0 = blockIdx.y * BN;

  f32x4 acc[4][NF] = {};

  for (int kt = 0; kt < K; kt += 64) {
#pragma unroll
    for (int h2 = 0; h2 < 2; ++h2) {
#pragma unroll
      for (int i = 0; i < 2; ++i) {
        const int li = i * 256 + t;
        const int row = li >> 2, cb = (li & 3) << 3;
        gload16(A + (size_t)(m0 + row) * K + kt + h2 * 32 + cb,
                (char*)lsA[h2] + (i * 256 + w * 64) * 16);
      }
#pragma unroll
      for (int i = 0; i < BN / 64; ++i) {
        const int li = i * 256 + t;
        const int row = li >> 2, cb = (li & 3) << 3;
        gload16(Bt + (size_t)(n0 + row) * K + kt + h2 * 32 + cb,
                (char*)lsB[h2] + (i * 256 + w * 64) * 16);
      }
    }
    __syncthreads();

#pragma unroll
    for (int h2 = 0; h2 < 2; ++h2) {
      bf16x8 af[4], bf_[NF];
#pragma unroll
      for (int m = 0; m < 4; ++m)
        af[m] = *reinterpret_cast<const bf16x8*>(
            &lsA[h2][(wr * 64 + m * 16 + l15) * 32 + lhi * 8]);
#pragma unroll
      for (int n = 0; n < NF; ++n)
        bf_[n] = *reinterpret_cast<const bf16x8*>(
            &lsB[h2][(wc * (BN / 2) + n * 16 + l15) * 32 + lhi * 8]);
#pragma unroll
      for (int m = 0; m < 4; ++m)
#pragma unroll
        for (int n = 0; n < NF; ++n)
          acc[m][n] = __builtin_amdgcn_mfma_f32_16x16x32_bf16(af[m], bf_[n], acc[m][n], 0, 0, 0);
    }
    __syncthreads();
  }

  if (Vt != nullptr && z == 2) {
    // transposed write: Vt[(b*1024 + c)][s], 4 consecutive tokens per quad
#pragma unroll
    for (int n = 0; n < NF; ++n) {
      const int c = n0 + wc * (BN / 2) + n * 16 + l15;
      const float bv = bias[c];
#pragma unroll
      for (int m = 0; m < 4; ++m) {
        const int r = m0 + wr * 64 + m * 16 + lhi * 4;
        ushort4 s4;
#pragma unroll
        for (int j = 0; j < 4; ++j) ((u16*)&s4)[j] = f2bf(acc[m][n][j] + bv);
        *reinterpret_cast<ushort4*>(
            &Vt[((size_t)((r >> 11) * 1024 + c)) * 2048 + (r & 2047)]) = s4;
      }
    }
    return;
  }

#pragma unroll
  for (int n = 0; n < NF; ++n) {
    const int c = n0 + wc * (BN / 2) + n * 16 + l15;
    const float bv = bias[c];
#pragma unroll
    for (int m = 0; m < 4; ++m)
#pragma unroll
      for (int j = 0; j < 4; ++j) {
        const int r = m0 + wr * 64 + m * 16 + lhi * 4 + j;
        store1(C, (size_t)r * N + c, (acc[m][n][j] + bv) * scl);
      }
  }
}

// ---------------- flash attention (32x32 MFMA, in-lane P, QK(t+1)||SM(t)) ------
// grid 512 flat, XCD-grouped. 4 waves/block, 32 q-rows/wave (q=lane&31). KVBLK=64.
// Pipeline: QK^T(t+1) (MFMA) issues BEFORE SM(t) (VALU). K LDS 3-deep (write
// lookahead +3), V 2-deep (+2), ONE barrier/tile. Mask bias pre-loads INITIALIZE
// the QK accumulator. P in-lane via sigma-staged lsV. T13 defer-max.
// Tree-reduced max/sum; pk2bf packed P. No s_setprio (R17 ablation: null).
__global__ __launch_bounds__(256, 2) void k_attn(
    const u16* __restrict__ Q, const u16* __restrict__ K, const u16* __restrict__ Vt,
    const float* __restrict__ MB, u16* __restrict__ O) {
  __shared__ u16 lsK[3][64][72];
  __shared__ u16 lsV[2][64][72];

  const int t = threadIdx.x, w = t >> 6, ln = t & 63;
  const int l31 = ln & 31, h = ln >> 5, h8 = h * 8;
  const int fid = blockIdx.x;                // 0..511
  const int xcd = fid & 7, slot = fid >> 3;  // 0..63
  const int pair = xcd * 4 + (slot >> 4);    // 0..31
  const int qt = slot & 15;
  const int hh = pair & 15, b = pair >> 4;

  const size_t rowQ = (size_t)b * 2048 + qt * 128 + w * 32;
  const int hc = hh * 64;

  const int srow = t >> 3, scol = (t & 7) << 3;
  const u16* Kg = K + ((size_t)b * 2048 + srow) * 1024 + hc + scol;
  const int half = t & 1;
  const int g16 = ((t & 7) >> 1) << 4;
  const u16* VgA = Vt + ((size_t)(b * 1024 + hc) + srow) * 2048 + g16 + 4 * half;
  const float* MBb = MB + b * 2048;

  bf16x8 qb[4];
#pragma unroll
  for (int ks = 0; ks < 4; ++ks)
    qb[ks] = *reinterpret_cast<const bf16x8*>(
        &Q[(rowQ + l31) * 1024 + hc + ks * 16 + h8]);

  f32x16 o[2];
#pragma unroll
  for (int i = 0; i < 16; ++i) { o[0][i] = 0.f; o[1][i] = 0.f; }
  float mrow = -1e30f, lsum = 0.f;

  // prologue: stage K(0..2) and V(0..1)
#pragma unroll
  for (int p = 0; p < 3; ++p) {
    const short8 a = *reinterpret_cast<const short8*>(Kg + (size_t)(p * 64) * 1024);
    const short8 c = *reinterpret_cast<const short8*>(Kg + (size_t)(p * 64 + 32) * 1024);
    *reinterpret_cast<short8*>(&lsK[p][srow][scol]) = a;
    *reinterpret_cast<short8*>(&lsK[p][32 + srow][scol]) = c;
  }
#pragma unroll
  for (int p = 0; p < 2; ++p) {
    const ushort4 a = *reinterpret_cast<const ushort4*>(VgA + p * 64);
    const ushort4 b4 = *reinterpret_cast<const ushort4*>(VgA + p * 64 + 8);
    const ushort4 c = *reinterpret_cast<const ushort4*>(VgA + 32 * 2048 + p * 64);
    const ushort4 d = *reinterpret_cast<const ushort4*>(VgA + 32 * 2048 + p * 64 + 8);
    *reinterpret_cast<ushort4*>(&lsV[p][srow][scol]) = a;
    *reinterpret_cast<ushort4*>(&lsV[p][srow][scol + 4]) = b4;
    *reinterpret_cast<ushort4*>(&lsV[p][32 + srow][scol]) = c;
    *reinterpret_cast<ushort4*>(&lsV[p][32 + srow][scol + 4]) = d;
  }
  __syncthreads();

  // QK(0) -> stA (bias-initialized accumulator)
  f32x16 stA[2], stB[2];
#pragma unroll
  for (int f = 0; f < 2; ++f)
#pragma unroll
    for (int rg = 0; rg < 4; ++rg) {
      const f32x4 bv = *reinterpret_cast<const f32x4*>(&MBb[f * 32 + rg * 8 + h * 4]);
#pragma unroll
      for (int jj = 0; jj < 4; ++jj) stA[f][rg * 4 + jj] = bv[jj];
    }
#pragma unroll
  for (int ks = 0; ks < 4; ++ks) {
    const bf16x8 kb0 = *reinterpret_cast<const bf16x8*>(&lsK[0][l31][ks * 16 + h8]);
    const bf16x8 kb1 = *reinterpret_cast<const bf16x8*>(&lsK[0][32 + l31][ks * 16 + h8]);
    stA[0] = __builtin_amdgcn_mfma_f32_32x32x16_bf16(kb0, qb[ks], stA[0], 0, 0, 0);
    stA[1] = __builtin_amdgcn_mfma_f32_32x32x16_bf16(kb1, qb[ks], stA[1], 0, 0, 0);
  }

#define ATTN_BODY(T, CUR, NXT, SW)                                                  \
  {                                                                                 \
    const int tK = ((T) + 3) & 31, tV = ((T) + 2) & 31, tB = ((T) + 1) & 31;        \
    const short8 rk0 = *reinterpret_cast<const short8*>(Kg + (size_t)(tK * 64) * 1024); \
    const short8 rk1 = *reinterpret_cast<const short8*>(Kg + (size_t)(tK * 64 + 32) * 1024); \
    const ushort4 rv0a = *reinterpret_cast<const ushort4*>(VgA + tV * 64);          \
    const ushort4 rv0b = *reinterpret_cast<const ushort4*>(VgA + tV * 64 + 8);      \
    const ushort4 rv1a = *reinterpret_cast<const ushort4*>(VgA + 32 * 2048 + tV * 64); \
    const ushort4 rv1b = *reinterpret_cast<const ushort4*>(VgA + 32 * 2048 + tV * 64 + 8); \
    const int sK = ((SW) == 2) ? 0 : (SW) + 1;                                      \
    _Pragma("unroll")                                                               \
    for (int f = 0; f < 2; ++f)                                                     \
      _Pragma("unroll")                                                             \
      for (int rg = 0; rg < 4; ++rg) {                                              \
        const f32x4 bv = *reinterpret_cast<const f32x4*>(                           \
            &MBb[tB * 64 + f * 32 + rg * 8 + h * 4]);                               \
        _Pragma("unroll")                                                           \
        for (int jj = 0; jj < 4; ++jj) NXT[f][rg * 4 + jj] = bv[jj];                \
      }                                                                             \
    _Pragma("unroll")                                                               \
    for (int ks = 0; ks < 4; ++ks) {                                                \
      const bf16x8 kb0 = *reinterpret_cast<const bf16x8*>(&lsK[sK][l31][ks * 16 + h8]); \
      const bf16x8 kb1 = *reinterpret_cast<const bf16x8*>(&lsK[sK][32 + l31][ks * 16 + h8]); \
      NXT[0] = __builtin_amdgcn_mfma_f32_32x32x16_bf16(kb0, qb[ks], NXT[0], 0, 0, 0); \
      NXT[1] = __builtin_amdgcn_mfma_f32_32x32x16_bf16(kb1, qb[ks], NXT[1], 0, 0, 0); \
    }                                                                               \
    float m0 = CUR[0][0], m1 = CUR[0][1], m2 = CUR[0][2], m3 = CUR[0][3];           \
    _Pragma("unroll")                                                               \
    for (int i = 4; i < 16; i += 4) {                                               \
      m0 = fmaxf(m0, CUR[0][i + 0]); m1 = fmaxf(m1, CUR[0][i + 1]);                 \
      m2 = fmaxf(m2, CUR[0][i + 2]); m3 = fmaxf(m3, CUR[0][i + 3]);                 \
    }                                                                               \
    _Pragma("unroll")                                                               \
    for (int i = 0; i < 16; i += 4) {                                               \
      m0 = fmaxf(m0, CUR[1][i + 0]); m1 = fmaxf(m1, CUR[1][i + 1]);                 \
      m2 = fmaxf(m2, CUR[1][i + 2]); m3 = fmaxf(m3, CUR[1][i + 3]);                 \
    }                                                                               \
    float tm = fmaxf(fmaxf(m0, m1), fmaxf(m2, m3));                                 \
    tm = fmaxf(tm, __shfl_xor(tm, 32, 64));                                         \
    const bool trig = tm > mrow + 8.f;                                              \
    if (__any(trig)) {                                                              \
      const float al = trig ? __builtin_amdgcn_exp2f(mrow - tm) : 1.f;              \
      if (trig) mrow = tm;                                                          \
      lsum *= al;                                                                   \
      _Pragma("unroll")                                                             \
      for (int f = 0; f < 2; ++f)                                                   \
        _Pragma("unroll")                                                           \
        for (int i = 0; i < 16; ++i) o[f][i] *= al;                                 \
    }                                                                               \
    float r0 = 0.f, r1 = 0.f, r2 = 0.f, r3 = 0.f;                                   \
    _Pragma("unroll")                                                               \
    for (int f = 0; f < 2; ++f)                                                     \
      _Pragma("unroll")                                                             \
      for (int i = 0; i < 16; i += 4) {                                             \
        const float p0 = __builtin_amdgcn_exp2f(CUR[f][i + 0] - mrow);              \
        const float p1 = __builtin_amdgcn_exp2f(CUR[f][i + 1] - mrow);              \
        const float p2 = __builtin_amdgcn_exp2f(CUR[f][i + 2] - mrow);              \
        const float p3 = __builtin_amdgcn_exp2f(CUR[f][i + 3] - mrow);              \
        CUR[f][i + 0] = p0; CUR[f][i + 1] = p1;                                     \
        CUR[f][i + 2] = p2; CUR[f][i + 3] = p3;                                     \
        r0 += p0; r1 += p1; r2 += p2; r3 += p3;                                     \
      }                                                                             \
    lsum += (r0 + r1) + (r2 + r3);                                                  \
    _Pragma("unroll")                                                               \
    for (int f = 0; f < 2; ++f) {                                                   \
      u32 pk[8];                                                                    \
      _Pragma("unroll")                                                             \
      for (int i = 0; i < 8; ++i)                                                   \
        pk[i] = pk2bf(CUR[f][2 * i], CUR[f][2 * i + 1]);                            \
      _Pragma("unroll")                                                             \
      for (int s = 0; s < 2; ++s) {                                                 \
        u32x4 pw;                                                                   \
        pw[0] = pk[4 * s + 0]; pw[1] = pk[4 * s + 1];                               \
        pw[2] = pk[4 * s + 2]; pw[3] = pk[4 * s + 3];                               \
        const bf16x8 pb = __builtin_bit_cast(bf16x8, pw);                           \
        const int ks = f * 2 + s;                                                   \
        _Pragma("unroll")                                                           \
        for (int df2 = 0; df2 < 2; ++df2) {                                         \
          const bf16x8 vt = *reinterpret_cast<const bf16x8*>(                       \
              &lsV[(T) & 1][df2 * 32 + l31][ks * 16 + h8]);                         \
          o[df2] = __builtin_amdgcn_mfma_f32_32x32x16_bf16(vt, pb, o[df2], 0, 0, 0); \
        }                                                                           \
      }                                                                             \
    }                                                                               \
    __syncthreads();                                                                \
    *reinterpret_cast<short8*>(&lsK[SW][srow][scol]) = rk0;                         \
    *reinterpret_cast<short8*>(&lsK[SW][32 + srow][scol]) = rk1;                    \
    *reinterpret_cast<ushort4*>(&lsV[(T) & 1][srow][scol]) = rv0a;                  \
    *reinterpret_cast<ushort4*>(&lsV[(T) & 1][srow][scol + 4]) = rv0b;              \
    *reinterpret_cast<ushort4*>(&lsV[(T) & 1][32 + srow][scol]) = rv1a;             \
    *reinterpret_cast<ushort4*>(&lsV[(T) & 1][32 + srow][scol + 4]) = rv1b;         \
  }

  int sw = 0;
  for (int t2 = 0; t2 < 32; t2 += 2) {
    ATTN_BODY(t2, stA, stB, sw);
    sw = (sw == 2) ? 0 : sw + 1;
    ATTN_BODY(t2 + 1, stB, stA, sw);
    sw = (sw == 2) ? 0 : sw + 1;
  }
#undef ATTN_BODY

  // epilogue: O[q][d], q = l31, d = df2*32 + 8*rg + 4h + jj
  const float ltot = lsum + __shfl_xor(lsum, 32, 64);
  const float inv = 1.f / ltot;
#pragma unroll
  for (int df2 = 0; df2 < 2; ++df2)
#pragma unroll
    for (int rg = 0; rg < 4; ++rg) {
      ushort4 s4;
      s4.x = bfc(o[df2][rg * 4 + 0] * inv);
      s4.y = bfc(o[df2][rg * 4 + 1] * inv);
      s4.z = bfc(o[df2][rg * 4 + 2] * inv);
      s4.w = bfc(o[df2][rg * 4 + 3] * inv);
      *reinterpret_cast<ushort4*>(
          &O[(rowQ + l31) * 1024 + hc + df2 * 32 + rg * 8 + h * 4]) = s4;
    }
}

extern "C" void kernel_launch(void* const* d_in, const int* in_sizes, int n_in,
                              void* d_out, int out_size, void* d_ws, size_t ws_size,
                              hipStream_t stream) {
  const float* x_q = (const float*)d_in[0];
  const float* x_k = (const float*)d_in[1];
  const float* x_v = (const float*)d_in[2];
  const int*   msk = (const int*)d_in[3];
  const float* Wq  = (const float*)d_in[4];
  const float* bq  = (const float*)d_in[5];
  const float* Wk  = (const float*)d_in[6];
  const float* bk  = (const float*)d_in[7];
  const float* Wv  = (const float*)d_in[8];
  const float* bv  = (const float*)d_in[9];
  const float* Wo  = (const float*)d_in[10];
  const float* bo  = (const float*)d_in[11];

  const size_t NTOK = 4096, H = 1024;
  u16* xbf  = (u16*)d_ws;            // 3 * 4096*1024 bf16
  u16* wt   = xbf + 3 * NTOK * H;    // 4 * 1024*1024 bf16 (transposed weights)
  u16* qkv  = wt  + 4 * H * H;       // Q,K row-major; V slot holds Vt (transposed)
  u16* aout = qkv + 3 * NTOK * H;    // 4096*1024 bf16
  float* mb = (float*)(aout + NTOK * H);  // 4096 floats
  u16* vtb  = qkv + 2 * NTOK * H;    // Vt[b*1024 + c][s] (reuses V slot)

  // prep: weights (z 0-3), mask bias (z 4), x fp32->bf16 (z 5-7)
  k_prep<<<dim3(32, 32, 8), dim3(32, 8), 0, stream>>>(
      Wq, Wk, Wv, Wo, wt, msk, mb, x_q, x_k, x_v, xbf);

  // Q,K,V = x{q,k,v} @ W{q,k,v} + b{q,k,v}; all-async staging, BK=64 dual-subtile.
  // Q scaled by 0.125*log2(e) for exp2 softmax; z==2 writes transposed Vt.
  const float qscale = 0.125f * 1.4426950408889634f;
  k_gemm_bt<u16, 128><<<dim3(32, 8, 3), dim3(256), 0, stream>>>(
      xbf, (long)(NTOK * H), wt, (long)(H * H), bq, bk, bv,
      qscale, 1.f, 1.f,
      qkv, (long)(NTOK * H), vtb, 4096, 1024, 1024);

  // attention (flat grid, XCD-grouped mapping inside)
  k_attn<<<dim3(512), dim3(256), 0, stream>>>(
      qkv, qkv + NTOK * H, vtb, mb, aout);

  // out = attn_out @ Wo + bo (fp32 output); BN=64 -> 512 blocks = 2/CU
  k_gemm_bt<float, 64><<<dim3(32, 16, 1), dim3(256), 0, stream>>>(
      aout, 0L, wt + 3 * H * H, 0L, bo, bo, bo,
      1.f, 1.f, 1.f,
      (float*)d_out, 0L, nullptr, 4096, 1024, 1024);
}